// Round 1
// 2132.804 us; speedup vs baseline: 1.3836x; 1.3836x over previous
//
#include <hip/hip_runtime.h>
#include <math.h>

#define BATCH 10
#define HID 128
#define OUT 7
#define MAXLEN 2048
#define NG 512
#define NT 1024
#define RINGD 512
#define OFF_STATE ((size_t)BATCH * MAXLEN * OUT)

typedef float float4v __attribute__((ext_vector_type(4)));

__device__ __forceinline__ float sigm_(float x) { return 1.0f / (1.0f + __expf(-x)); }
__device__ __forceinline__ float tanh_(float x) { return 1.0f - 2.0f / (1.0f + __expf(2.0f * x)); }

// Butterfly sum over lanes {l^1, l^2, l^4}: every lane of each 8-lane group
// ends with the group total. Pure VALU (DPP), no LDS pipe traffic.
// xor1 = quad_perm [1,0,3,2] (0xB1); xor2 = quad_perm [2,3,0,1] (0x4E);
// xor4 = row_half_mirror (0x141), valid because quads are uniform after xor1+xor2.
__device__ __forceinline__ float grp8_sum(float v) {
    v += __int_as_float(__builtin_amdgcn_update_dpp(0, __float_as_int(v), 0xB1, 0xF, 0xF, true));
    v += __int_as_float(__builtin_amdgcn_update_dpp(0, __float_as_int(v), 0x4E, 0xF, 0xF, true));
    v += __int_as_float(__builtin_amdgcn_update_dpp(0, __float_as_int(v), 0x141, 0xF, 0xF, true));
    return v;
}

__global__
__attribute__((amdgpu_flat_work_group_size(NT, NT), amdgpu_waves_per_eu(4, 4)))
void decoder_rnn_kernel(const float* __restrict__ h0,
                        const float* __restrict__ c0,
                        const float* __restrict__ tonehot,   // (MAXLEN+1, 1, OUT)
                        const void*  __restrict__ tf_raw,    // bool mask, int8 or int32
                        const float* __restrict__ Wih,       // (4H, OUT)
                        const float* __restrict__ Whh,       // (4H, H)
                        const float* __restrict__ bih,
                        const float* __restrict__ bhh,
                        const float* __restrict__ Wout,      // (OUT, H)
                        const float* __restrict__ bout,
                        float* __restrict__ out)
{
    // R17: replace 16x-row-redundant f16-split MFMA matvec with fp32 VALU
    // matvec, weights register-resident. Lane (wv, grp=lane>>3, ksl=lane&7)
    // owns gates [wv*32+grp*4 .. +3] over K slice [16*ksl .. +15].
    __shared__ __align__(16) float h_lds[HID];       // fp32 h (no f16 split needed)
    __shared__ __align__(16) float gates_lds[NG];    // pre-bias gates
    __shared__ float wih_eff[OUT * NG];              // Wih^T + bias, [x][g]
    __shared__ float ring[RINGD][OUT];               // RAW logits (bout added at flush)
    __shared__ unsigned char tgt8[MAXLEN];
    __shared__ unsigned char tf8[MAXLEN];
    __shared__ int tf_byte_mode;

    const int t    = threadIdx.x;
    const int lane = t & 63;
    const int wv   = t >> 6;
    const int ksl  = lane & 7;        // K slice index
    const int grp  = lane >> 3;       // 4-gate group within wave
    const int b    = blockIdx.x;
    const int gbase = wv * 32 + grp * 4;

    // ---- persistent fp32 W_hh fragments: 4 gates x 16 K per lane (64 VGPR) ----
    float4v wgt[4][4];
    #pragma unroll
    for (int j = 0; j < 4; j++)
        #pragma unroll
        for (int c = 0; c < 4; c++)
            wgt[j][c] = *(const float4v*)&Whh[(size_t)(gbase + j) * HID + ksl * 16 + c * 4];

    // logit weights: waves 0,1, lane group grp -> logit row grp (7 used of 8)
    float4v lw[4];
    #pragma unroll
    for (int c = 0; c < 4; c++) { float4v z = {0.f, 0.f, 0.f, 0.f}; lw[c] = z; }
    if (wv < 2 && grp < OUT) {
        #pragma unroll
        for (int c = 0; c < 4; c++)
            lw[c] = *(const float4v*)&Wout[(size_t)grp * HID + ksl * 16 + c * 4];
    }

    float boutr[OUT];
    #pragma unroll
    for (int j = 0; j < OUT; j++) boutr[j] = bout[j];

    // ---- LDS setup ----
    for (int idx = t; idx < OUT * NG; idx += NT) {
        int x = idx >> 9, g = idx & (NG - 1);
        wih_eff[idx] = Wih[g * OUT + x] + bih[g] + bhh[g];
    }
    if (t == 0) tf_byte_mode = 0;
    for (int s = t; s < MAXLEN; s += NT) {
        const float* row = tonehot + (size_t)(s + 1) * OUT;
        int idx = 0;
        #pragma unroll
        for (int j = 0; j < OUT; j++) if (row[j] > 0.5f) idx = j;
        tgt8[s] = (unsigned char)idx;
    }
    __syncthreads();
    {   // tf_mask layout detection (int8 bool vs int32) — proven R1-R16
        const unsigned char* tb = (const unsigned char*)tf_raw;
        int mis = 0;
        for (int p = t; p < MAXLEN; p += NT)
            if ((p & 3) && tb[p]) mis = 1;
        if (mis) atomicOr(&tf_byte_mode, 1);
    }
    // ---- state init ----
    float c_reg = 0.f, hv = 0.f;
    if (t < HID) {
        hv    = h0[b * HID + t];
        c_reg = c0[b * HID + t];
        h_lds[t] = hv;
    }
    __syncthreads();
    if (tf_byte_mode) {
        const unsigned char* tb = (const unsigned char*)tf_raw;
        for (int s = t; s < MAXLEN; s += NT) tf8[s] = (tb[s] != 0);
    } else {
        const int* ti = (const int*)tf_raw;
        for (int s = t; s < MAXLEN; s += NT) tf8[s] = (ti[s] != 0);
    }
    __syncthreads();

    float* outlp = out + (size_t)b * MAXLEN * OUT;

    for (int s = 0; s < MAXLEN; s++) {
        // ---- phase 1: fp32 VALU matvec (gates + logits), DPP reduce ----
        float4v hc[4];
        #pragma unroll
        for (int c = 0; c < 4; c++)
            hc[c] = *(const float4v*)&h_lds[ksl * 16 + c * 4];  // 8-way bcast, conflict-free

        float a0 = 0.f, a1 = 0.f, a2 = 0.f, a3 = 0.f;
        #pragma unroll
        for (int c = 0; c < 4; c++)
            #pragma unroll
            for (int e = 0; e < 4; e++) {
                const float hval = hc[c][e];
                a0 = fmaf(wgt[0][c][e], hval, a0);
                a1 = fmaf(wgt[1][c][e], hval, a1);
                a2 = fmaf(wgt[2][c][e], hval, a2);
                a3 = fmaf(wgt[3][c][e], hval, a3);
            }
        float al = 0.f;
        if (wv < 2) {   // wave-uniform: logits ride on the already-loaded h chunks
            #pragma unroll
            for (int c = 0; c < 4; c++)
                #pragma unroll
                for (int e = 0; e < 4; e++)
                    al = fmaf(lw[c][e], hc[c][e], al);
            al = grp8_sum(al);   // lane holds raw logit[grp]
        }
        a0 = grp8_sum(a0);
        a1 = grp8_sum(a1);
        a2 = grp8_sum(a2);
        a3 = grp8_sum(a3);
        if (ksl == 0) {
            float4v g4;
            g4[0] = a0; g4[1] = a1; g4[2] = a2; g4[3] = a3;
            *(float4v*)&gates_lds[gbase] = g4;   // 8 lanes x b128 = 128B contiguous
        }
        __syncthreads();   // A: gates ready; h_lds reads done

        // ---- phase 2a: pointwise (waves 0,1); logits arrive in-register ----
        if (t < HID) {
            int xsel = OUT - 1;
            if (s > 0) {
                float lg[OUT];
                lg[0] = __int_as_float(__builtin_amdgcn_readlane(__float_as_int(al),  0)) + boutr[0];
                lg[1] = __int_as_float(__builtin_amdgcn_readlane(__float_as_int(al),  8)) + boutr[1];
                lg[2] = __int_as_float(__builtin_amdgcn_readlane(__float_as_int(al), 16)) + boutr[2];
                lg[3] = __int_as_float(__builtin_amdgcn_readlane(__float_as_int(al), 24)) + boutr[3];
                lg[4] = __int_as_float(__builtin_amdgcn_readlane(__float_as_int(al), 32)) + boutr[4];
                lg[5] = __int_as_float(__builtin_amdgcn_readlane(__float_as_int(al), 40)) + boutr[5];
                lg[6] = __int_as_float(__builtin_amdgcn_readlane(__float_as_int(al), 48)) + boutr[6];
                float bv = lg[0]; int bi = 0;
                #pragma unroll
                for (int j = 1; j < OUT; j++) if (lg[j] > bv) { bv = lg[j]; bi = j; }
                xsel = tf8[s - 1] ? (int)tgt8[s - 1] : bi;
                if (wv == 0 && ksl == 0 && grp < OUT)
                    ring[(s - 1) & (RINGD - 1)][grp] = al;   // raw logit (no bout)
            }
            const int xo = xsel * NG;
            float ri = gates_lds[t]           + wih_eff[xo + t];
            float rf = gates_lds[HID + t]     + wih_eff[xo + HID + t];
            float rg = gates_lds[2 * HID + t] + wih_eff[xo + 2 * HID + t];
            float ro = gates_lds[3 * HID + t] + wih_eff[xo + 3 * HID + t];
            float cn = sigm_(rf) * c_reg + sigm_(ri) * tanh_(rg);
            c_reg = cn;
            hv = sigm_(ro) * tanh_(cn);
            h_lds[t] = hv;
        } else if (t >= 512 && t < 768 && (s & 255) == 1 && s > 256) {
            // ---- phase 2b: deferred log-softmax flush (waves 8-11) ----
            const int step = (s - 257) + (t - 512);
            const int slot = step & (RINGD - 1);
            float v[OUT];
            #pragma unroll
            for (int j = 0; j < OUT; j++) v[j] = ring[slot][j] + boutr[j];
            float mx = v[0];
            #pragma unroll
            for (int j = 1; j < OUT; j++) mx = fmaxf(mx, v[j]);
            float sum = 0.f;
            #pragma unroll
            for (int j = 0; j < OUT; j++) sum += __expf(v[j] - mx);
            const float lse = mx + __logf(sum);
            float* dst = outlp + (size_t)step * OUT;
            #pragma unroll
            for (int j = 0; j < OUT; j++) dst[j] = v[j] - lse;
        }
        __syncthreads();   // C: h(s+1) visible
    }

    // ---- epilogue: raw logits for step 2047 from final h ----
    if (wv < 2) {
        float al = 0.f;
        #pragma unroll
        for (int c = 0; c < 4; c++) {
            float4v hcv = *(const float4v*)&h_lds[ksl * 16 + c * 4];
            #pragma unroll
            for (int e = 0; e < 4; e++) al = fmaf(lw[c][e], hcv[e], al);
        }
        al = grp8_sum(al);
        if (wv == 0 && ksl == 0 && grp < OUT)
            ring[(MAXLEN - 1) & (RINGD - 1)][grp] = al;
    }
    __syncthreads();
    if (t < 256) {   // final flush: steps 1792..2047
        const int step = (MAXLEN - 256) + t;
        const int slot = step & (RINGD - 1);
        float v[OUT];
        #pragma unroll
        for (int j = 0; j < OUT; j++) v[j] = ring[slot][j] + boutr[j];
        float mx = v[0];
        #pragma unroll
        for (int j = 1; j < OUT; j++) mx = fmaxf(mx, v[j]);
        float sum = 0.f;
        #pragma unroll
        for (int j = 0; j < OUT; j++) sum += __expf(v[j] - mx);
        const float lse = mx + __logf(sum);
        float* dst = outlp + (size_t)step * OUT;
        #pragma unroll
        for (int j = 0; j < OUT; j++) dst[j] = v[j] - lse;
    }
    if (t < HID) {
        out[OFF_STATE + b * HID + t] = hv;                        // hT
        out[OFF_STATE + BATCH * HID + b * HID + t] = c_reg;       // cT
    }
}

extern "C" void kernel_launch(void* const* d_in, const int* in_sizes, int n_in,
                              void* d_out, int out_size, void* d_ws, size_t ws_size,
                              hipStream_t stream) {
    const float* h0    = (const float*)d_in[0];
    const float* c0    = (const float*)d_in[1];
    const float* toh   = (const float*)d_in[2];
    const void*  tfm   = (const void*) d_in[3];
    const float* Wih   = (const float*)d_in[4];
    const float* Whh   = (const float*)d_in[5];
    const float* bih   = (const float*)d_in[6];
    const float* bhh   = (const float*)d_in[7];
    const float* Wout  = (const float*)d_in[8];
    const float* bout  = (const float*)d_in[9];
    float* out = (float*)d_out;

    decoder_rnn_kernel<<<dim3(BATCH), dim3(NT), 0, stream>>>(
        h0, c0, toh, tfm, Wih, Whh, bih, bhh, Wout, bout, out);
}

// Round 2
// 1955.287 us; speedup vs baseline: 1.5092x; 1.0908x over previous
//
#include <hip/hip_runtime.h>
#include <math.h>

#define BATCH 10
#define HID 128
#define OUT 7
#define MAXLEN 2048
#define NG 512
#define NT 512
#define RINGD 512
#define OFF_STATE ((size_t)BATCH * MAXLEN * OUT)

typedef float float2v __attribute__((ext_vector_type(2)));
typedef float float4v __attribute__((ext_vector_type(4)));

__device__ __forceinline__ float sigm_(float x) { return 1.0f / (1.0f + __expf(-x)); }
__device__ __forceinline__ float tanh_(float x) { return 1.0f - 2.0f / (1.0f + __expf(2.0f * x)); }

// Butterfly sum over lanes {l^1, l^2, l^4}: every lane of each 8-lane group
// ends with the group total. Pure VALU (DPP), no LDS pipe traffic.
__device__ __forceinline__ float grp8_sum(float v) {
    v += __int_as_float(__builtin_amdgcn_update_dpp(0, __float_as_int(v), 0xB1, 0xF, 0xF, true));  // xor1
    v += __int_as_float(__builtin_amdgcn_update_dpp(0, __float_as_int(v), 0x4E, 0xF, 0xF, true));  // xor2
    v += __int_as_float(__builtin_amdgcn_update_dpp(0, __float_as_int(v), 0x141, 0xF, 0xF, true)); // xor4 (row_half_mirror)
    return v;
}

__global__
__attribute__((amdgpu_flat_work_group_size(NT, NT), amdgpu_waves_per_eu(2, 2)))
void decoder_rnn_kernel(const float* __restrict__ h0,
                        const float* __restrict__ c0,
                        const float* __restrict__ tonehot,   // (MAXLEN+1, 1, OUT)
                        const void*  __restrict__ tf_raw,    // bool mask, int8 or int32
                        const float* __restrict__ Wih,       // (4H, OUT)
                        const float* __restrict__ Whh,       // (4H, H)
                        const float* __restrict__ bih,
                        const float* __restrict__ bhh,
                        const float* __restrict__ Wout,      // (OUT, H)
                        const float* __restrict__ bout,
                        float* __restrict__ out)
{
    // R18: 8 waves (halves LDS-pipe traffic), conflict-free h layout
    // (lane reads h[c*32+ksl*4], 8 addrs tile all 32 banks), v_pk_fma_f32
    // matvec (float2 + elementwise_fma), argmax hoisted before barrier A.
    // Lane (wv, grp=lane>>3, ksl=lane&7) owns gates [wv*64+grp*8 .. +7]
    // over K subset {c*32 + ksl*4 .. +3 : c=0..3}.
    __shared__ __align__(16) float h_lds[HID];
    __shared__ __align__(16) float gates_lds[NG];
    __shared__ float wih_eff[OUT * NG];              // Wih^T + bias, [x][g]
    __shared__ float ring[RINGD][OUT];               // RAW logits (bout added at flush)
    __shared__ unsigned char tgt8[MAXLEN];
    __shared__ unsigned char tf8[MAXLEN];
    __shared__ int tf_byte_mode;

    const int t    = threadIdx.x;
    const int lane = t & 63;
    const int wv   = t >> 6;          // 0..7
    const int ksl  = lane & 7;        // K slice index
    const int grp  = lane >> 3;       // 8-gate group within wave
    const int b    = blockIdx.x;
    const int gbase = wv * 64 + grp * 8;

    // ---- persistent fp32 W_hh fragments: 8 gates x 16 K per lane (128 VGPR) ----
    // K-pair p -> elements kk(p), kk(p)+1 with kk(p) = (p>>1)*32 + ksl*4 + (p&1)*2
    float2v wgt2[8][8];
    #pragma unroll
    for (int g = 0; g < 8; g++)
        #pragma unroll
        for (int p = 0; p < 8; p++) {
            const int kk = (p >> 1) * 32 + ksl * 4 + (p & 1) * 2;
            wgt2[g][p] = *(const float2v*)&Whh[(size_t)(gbase + g) * HID + kk];
        }

    // logit weights: waves 0,1, lane group grp -> logit row grp (7 used of 8)
    float2v lw2[8];
    #pragma unroll
    for (int p = 0; p < 8; p++) { float2v z = {0.f, 0.f}; lw2[p] = z; }
    if (wv < 2 && grp < OUT) {
        #pragma unroll
        for (int p = 0; p < 8; p++) {
            const int kk = (p >> 1) * 32 + ksl * 4 + (p & 1) * 2;
            lw2[p] = *(const float2v*)&Wout[(size_t)grp * HID + kk];
        }
    }

    float boutr[OUT];
    #pragma unroll
    for (int j = 0; j < OUT; j++) boutr[j] = bout[j];

    // ---- LDS setup ----
    for (int idx = t; idx < OUT * NG; idx += NT) {
        int x = idx >> 9, g = idx & (NG - 1);
        wih_eff[idx] = Wih[g * OUT + x] + bih[g] + bhh[g];
    }
    if (t == 0) tf_byte_mode = 0;
    for (int s = t; s < MAXLEN; s += NT) {
        const float* row = tonehot + (size_t)(s + 1) * OUT;
        int idx = 0;
        #pragma unroll
        for (int j = 0; j < OUT; j++) if (row[j] > 0.5f) idx = j;
        tgt8[s] = (unsigned char)idx;
    }
    __syncthreads();
    {   // tf_mask layout detection (int8 bool vs int32) — proven R1-R16
        const unsigned char* tb = (const unsigned char*)tf_raw;
        int mis = 0;
        for (int p = t; p < MAXLEN; p += NT)
            if ((p & 3) && tb[p]) mis = 1;
        if (mis) atomicOr(&tf_byte_mode, 1);
    }
    // ---- state init ----
    float c_reg = 0.f, hv = 0.f;
    if (t < HID) {
        hv    = h0[b * HID + t];
        c_reg = c0[b * HID + t];
        h_lds[t] = hv;
    }
    __syncthreads();
    if (tf_byte_mode) {
        const unsigned char* tb = (const unsigned char*)tf_raw;
        for (int s = t; s < MAXLEN; s += NT) tf8[s] = (tb[s] != 0);
    } else {
        const int* ti = (const int*)tf_raw;
        for (int s = t; s < MAXLEN; s += NT) tf8[s] = (ti[s] != 0);
    }
    __syncthreads();

    float* outlp = out + (size_t)b * MAXLEN * OUT;

    for (int s = 0; s < MAXLEN; s++) {
        // ---- phase 1: packed-fp32 matvec, DPP reduce, pre-barrier argmax ----
        float4v hc[4];
        #pragma unroll
        for (int c = 0; c < 4; c++)
            hc[c] = *(const float4v*)&h_lds[c * 32 + ksl * 4];  // conflict-free

        float2v acc[8];
        #pragma unroll
        for (int g = 0; g < 8; g++) { float2v z = {0.f, 0.f}; acc[g] = z; }
        #pragma unroll
        for (int p = 0; p < 8; p++) {
            const float2v hp = (p & 1)
                ? __builtin_shufflevector(hc[p >> 1], hc[p >> 1], 2, 3)
                : __builtin_shufflevector(hc[p >> 1], hc[p >> 1], 0, 1);
            #pragma unroll
            for (int g = 0; g < 8; g++)
                acc[g] = __builtin_elementwise_fma(wgt2[g][p], hp, acc[g]);
        }
        float a[8];
        #pragma unroll
        for (int g = 0; g < 8; g++) a[g] = grp8_sum(acc[g][0] + acc[g][1]);

        int xsel = OUT - 1;
        if (wv < 2) {   // logits ride on the already-loaded h chunks; argmax pre-barrier
            float2v accl = {0.f, 0.f};
            #pragma unroll
            for (int p = 0; p < 8; p++) {
                const float2v hp = (p & 1)
                    ? __builtin_shufflevector(hc[p >> 1], hc[p >> 1], 2, 3)
                    : __builtin_shufflevector(hc[p >> 1], hc[p >> 1], 0, 1);
                accl = __builtin_elementwise_fma(lw2[p], hp, accl);
            }
            const float al = grp8_sum(accl[0] + accl[1]);   // lane holds raw logit[grp]
            if (s > 0) {
                float lg[OUT];
                lg[0] = __int_as_float(__builtin_amdgcn_readlane(__float_as_int(al),  0)) + boutr[0];
                lg[1] = __int_as_float(__builtin_amdgcn_readlane(__float_as_int(al),  8)) + boutr[1];
                lg[2] = __int_as_float(__builtin_amdgcn_readlane(__float_as_int(al), 16)) + boutr[2];
                lg[3] = __int_as_float(__builtin_amdgcn_readlane(__float_as_int(al), 24)) + boutr[3];
                lg[4] = __int_as_float(__builtin_amdgcn_readlane(__float_as_int(al), 32)) + boutr[4];
                lg[5] = __int_as_float(__builtin_amdgcn_readlane(__float_as_int(al), 40)) + boutr[5];
                lg[6] = __int_as_float(__builtin_amdgcn_readlane(__float_as_int(al), 48)) + boutr[6];
                float bv = lg[0]; int bi = 0;
                #pragma unroll
                for (int j = 1; j < OUT; j++) if (lg[j] > bv) { bv = lg[j]; bi = j; }
                xsel = tf8[s - 1] ? (int)tgt8[s - 1] : bi;
                if (wv == 0 && ksl == 0 && grp < OUT)
                    ring[(s - 1) & (RINGD - 1)][grp] = al;   // raw logit
            }
        }
        if (ksl == 0) {
            float4v g4a, g4b;
            g4a[0] = a[0]; g4a[1] = a[1]; g4a[2] = a[2]; g4a[3] = a[3];
            g4b[0] = a[4]; g4b[1] = a[5]; g4b[2] = a[6]; g4b[3] = a[7];
            *(float4v*)&gates_lds[gbase]     = g4a;
            *(float4v*)&gates_lds[gbase + 4] = g4b;
        }
        __syncthreads();   // A: gates ready; h_lds reads done

        // ---- phase 2a: pointwise (waves 0,1); xsel already in-register ----
        if (t < HID) {
            const int xo = xsel * NG;
            float ri = gates_lds[t]           + wih_eff[xo + t];
            float rf = gates_lds[HID + t]     + wih_eff[xo + HID + t];
            float rg = gates_lds[2 * HID + t] + wih_eff[xo + 2 * HID + t];
            float ro = gates_lds[3 * HID + t] + wih_eff[xo + 3 * HID + t];
            float cn = sigm_(rf) * c_reg + sigm_(ri) * tanh_(rg);
            c_reg = cn;
            hv = sigm_(ro) * tanh_(cn);
            h_lds[t] = hv;
        } else if (t >= 256 && (s & 255) == 1 && s > 256) {
            // ---- phase 2b: deferred log-softmax flush (waves 4-7) ----
            const int step = (s - 257) + (t - 256);      // slot-disjoint from (s-1)
            const int slot = step & (RINGD - 1);
            float v[OUT];
            #pragma unroll
            for (int j = 0; j < OUT; j++) v[j] = ring[slot][j] + boutr[j];
            float mx = v[0];
            #pragma unroll
            for (int j = 1; j < OUT; j++) mx = fmaxf(mx, v[j]);
            float sum = 0.f;
            #pragma unroll
            for (int j = 0; j < OUT; j++) sum += __expf(v[j] - mx);
            const float lse = mx + __logf(sum);
            float* dst = outlp + (size_t)step * OUT;
            #pragma unroll
            for (int j = 0; j < OUT; j++) dst[j] = v[j] - lse;
        }
        __syncthreads();   // C: h(s+1) visible
    }

    // ---- epilogue: raw logits for step 2047 from final h ----
    if (wv < 2) {
        float2v accl = {0.f, 0.f};
        #pragma unroll
        for (int p = 0; p < 8; p++) {
            const int kk = (p >> 1) * 32 + ksl * 4 + (p & 1) * 2;
            const float2v hp = *(const float2v*)&h_lds[kk];
            accl = __builtin_elementwise_fma(lw2[p], hp, accl);
        }
        const float al = grp8_sum(accl[0] + accl[1]);
        if (wv == 0 && ksl == 0 && grp < OUT)
            ring[(MAXLEN - 1) & (RINGD - 1)][grp] = al;
    }
    __syncthreads();
    if (t < 256) {   // final flush: steps 1792..2047
        const int step = (MAXLEN - 256) + t;
        const int slot = step & (RINGD - 1);
        float v[OUT];
        #pragma unroll
        for (int j = 0; j < OUT; j++) v[j] = ring[slot][j] + boutr[j];
        float mx = v[0];
        #pragma unroll
        for (int j = 1; j < OUT; j++) mx = fmaxf(mx, v[j]);
        float sum = 0.f;
        #pragma unroll
        for (int j = 0; j < OUT; j++) sum += __expf(v[j] - mx);
        const float lse = mx + __logf(sum);
        float* dst = outlp + (size_t)step * OUT;
        #pragma unroll
        for (int j = 0; j < OUT; j++) dst[j] = v[j] - lse;
    }
    if (t < HID) {
        out[OFF_STATE + b * HID + t] = hv;                        // hT
        out[OFF_STATE + BATCH * HID + b * HID + t] = c_reg;       // cT
    }
}

extern "C" void kernel_launch(void* const* d_in, const int* in_sizes, int n_in,
                              void* d_out, int out_size, void* d_ws, size_t ws_size,
                              hipStream_t stream) {
    const float* h0    = (const float*)d_in[0];
    const float* c0    = (const float*)d_in[1];
    const float* toh   = (const float*)d_in[2];
    const void*  tfm   = (const void*) d_in[3];
    const float* Wih   = (const float*)d_in[4];
    const float* Whh   = (const float*)d_in[5];
    const float* bih   = (const float*)d_in[6];
    const float* bhh   = (const float*)d_in[7];
    const float* Wout  = (const float*)d_in[8];
    const float* bout  = (const float*)d_in[9];
    float* out = (float*)d_out;

    decoder_rnn_kernel<<<dim3(BATCH), dim3(NT), 0, stream>>>(
        h0, c0, toh, tfm, Wih, Whh, bih, bhh, Wout, bout, out);
}